// Round 1
// baseline (1098.375 us; speedup 1.0000x reference)
//
#include <hip/hip_runtime.h>
#include <math.h>

#define FEAT 128
#define NRBF 20
#define NCONV 3
#define PI_F 3.14159265358979323846f

typedef __attribute__((ext_vector_type(8))) short short8;
typedef __attribute__((ext_vector_type(4))) float floatx4;
typedef unsigned short ushort_t;

__device__ inline float b2f(unsigned short u) {
    union { unsigned int i; float f; } c; c.i = ((unsigned int)u) << 16; return c.f;
}
__device__ inline unsigned short f2b(float x) {
    union { float f; unsigned int i; } c; c.f = x;
    unsigned int u = c.i;
    return (unsigned short)((u + 0x7fffu + ((u >> 16) & 1u)) >> 16);
}

// ---------------------------------------------------------------------------
// Fused 2-layer MLP: out[M,384] = silu(A1 @ W1^T + b1) @ W2^T + b2
// A1 = s[M,128] (phi mode) or [s | norm(vv)] [M,256] (gate mode, vv != null).
// phi mode writes PACKED bf16 out: out_b[m*512 + g*4 + c]  (g=n&127, c=n>>7)
// so edge_aggr can gather all 3 chunks with ONE ushort4 load.
// ---------------------------------------------------------------------------
__global__ __launch_bounds__(256) void mlp_fused_kernel(
    const float* __restrict__ s, const float* __restrict__ vv,
    const ushort_t* __restrict__ W1h, const ushort_t* __restrict__ W1l,
    const float* __restrict__ b1,
    const ushort_t* __restrict__ W2h, const ushort_t* __restrict__ W2l,
    const float* __restrict__ b2,
    ushort_t* __restrict__ out_b, float* __restrict__ out_f,
    int M, int K1, int SP)
{
    __shared__ __align__(16) ushort_t Ah[128 * 40];
    __shared__ __align__(16) ushort_t Al[128 * 40];
    __shared__ __align__(16) ushort_t Wh[128 * 40];
    __shared__ __align__(16) ushort_t Wl[128 * 40];
    __shared__ __align__(16) ushort_t Hh[128 * 136];
    __shared__ __align__(16) ushort_t Hl[128 * 136];

    const int t    = threadIdx.x;
    const int m0   = blockIdx.x * 128;
    const int wv   = t >> 6;
    const int lane = t & 63;
    const int wm   = (wv >> 1) * 64;
    const int wn   = (wv & 1) * 64;
    const int lr   = lane & 15;
    const int lk   = (lane >> 4) * 8;
    const int quad = lane >> 4;
    const int arow = t >> 3;          // 0..31, 4 passes of 32 rows
    const int acol = (t & 7) * 4;     // fp32 x4
    const int wrow = t >> 2;          // 0..63, 2 passes of 64 rows
    const int wcol = (t & 3) * 8;     // ushort x8

    floatx4 acc[4][4] = {};

    // ---- stage 1: h = silu(A1 @ W1^T + b1) ----
    for (int k0 = 0; k0 < K1; k0 += 32) {
        #pragma unroll
        for (int h = 0; h < 4; ++h) {
            int r = arow + h * 32;
            int m = m0 + r; if (m >= M) m = M - 1;   // clamp tail
            float xs[4];
            if (k0 < 128) {
                float4 av = *(const float4*)(s + (long)m * 128 + k0 + acol);
                xs[0] = av.x; xs[1] = av.y; xs[2] = av.z; xs[3] = av.w;
            } else {
                long base = (long)m * 128 + (k0 - 128 + acol);
                float4 a0 = *(const float4*)(vv + base);
                float4 a1 = *(const float4*)(vv + (long)SP + base);
                float4 a2 = *(const float4*)(vv + 2 * (long)SP + base);
                xs[0] = sqrtf(a0.x * a0.x + a1.x * a1.x + a2.x * a2.x);
                xs[1] = sqrtf(a0.y * a0.y + a1.y * a1.y + a2.y * a2.y);
                xs[2] = sqrtf(a0.z * a0.z + a1.z * a1.z + a2.z * a2.z);
                xs[3] = sqrtf(a0.w * a0.w + a1.w * a1.w + a2.w * a2.w);
            }
            unsigned short hh[4], ll[4];
            #pragma unroll
            for (int q = 0; q < 4; ++q) {
                hh[q] = f2b(xs[q]);
                ll[q] = f2b(xs[q] - b2f(hh[q]));
            }
            *(ushort4*)(&Ah[r * 40 + acol]) = make_ushort4(hh[0], hh[1], hh[2], hh[3]);
            *(ushort4*)(&Al[r * 40 + acol]) = make_ushort4(ll[0], ll[1], ll[2], ll[3]);
        }
        #pragma unroll
        for (int h = 0; h < 2; ++h) {
            int r = wrow + h * 64;
            *(uint4*)(&Wh[r * 40 + wcol]) =
                *(const uint4*)(W1h + (long)r * K1 + k0 + wcol);
            *(uint4*)(&Wl[r * 40 + wcol]) =
                *(const uint4*)(W1l + (long)r * K1 + k0 + wcol);
        }
        __syncthreads();
        short8 af[4], alf[4], wf[4], wlf[4];
        #pragma unroll
        for (int i = 0; i < 4; ++i) {
            af[i]  = *(const short8*)(&Ah[(wm + i * 16 + lr) * 40 + lk]);
            alf[i] = *(const short8*)(&Al[(wm + i * 16 + lr) * 40 + lk]);
            wf[i]  = *(const short8*)(&Wh[(wn + i * 16 + lr) * 40 + lk]);
            wlf[i] = *(const short8*)(&Wl[(wn + i * 16 + lr) * 40 + lk]);
        }
        #pragma unroll
        for (int i = 0; i < 4; ++i)
            #pragma unroll
            for (int j = 0; j < 4; ++j) {
                acc[i][j] = __builtin_amdgcn_mfma_f32_16x16x32_bf16(
                    af[i], wf[j], acc[i][j], 0, 0, 0);
                acc[i][j] = __builtin_amdgcn_mfma_f32_16x16x32_bf16(
                    af[i], wlf[j], acc[i][j], 0, 0, 0);
                acc[i][j] = __builtin_amdgcn_mfma_f32_16x16x32_bf16(
                    alf[i], wf[j], acc[i][j], 0, 0, 0);
            }
        __syncthreads();
    }

    // stage-1 epilogue -> h in LDS (hi/lo), C/D layout col=lane&15, row=quad*4+r
    #pragma unroll
    for (int i = 0; i < 4; ++i)
        #pragma unroll
        for (int r = 0; r < 4; ++r) {
            int mrow = wm + i * 16 + quad * 4 + r;
            #pragma unroll
            for (int j = 0; j < 4; ++j) {
                int kcol = wn + j * 16 + lr;
                float x = acc[i][j][r] + b1[kcol];
                x *= 1.f / (1.f + __expf(-x));
                unsigned short hh = f2b(x);
                Hh[mrow * 136 + kcol] = hh;
                Hl[mrow * 136 + kcol] = f2b(x - b2f(hh));
            }
        }

    // ---- stage 2: out = h @ W2^T + b2, 3 n-tiles of 128 ----
    for (int nt = 0; nt < 3; ++nt) {
        #pragma unroll
        for (int i = 0; i < 4; ++i)
            #pragma unroll
            for (int j = 0; j < 4; ++j)
                #pragma unroll
                for (int q = 0; q < 4; ++q) acc[i][j][q] = 0.f;
        for (int k0 = 0; k0 < 128; k0 += 32) {
            __syncthreads();   // guard Wh/Wl overwrite (and H writes on 1st pass)
            #pragma unroll
            for (int h = 0; h < 2; ++h) {
                int r = wrow + h * 64;
                long wo = (long)(nt * 128 + r) * 128;
                *(uint4*)(&Wh[r * 40 + wcol]) = *(const uint4*)(W2h + wo + k0 + wcol);
                *(uint4*)(&Wl[r * 40 + wcol]) = *(const uint4*)(W2l + wo + k0 + wcol);
            }
            __syncthreads();
            short8 af[4], alf[4], wf[4], wlf[4];
            #pragma unroll
            for (int i = 0; i < 4; ++i) {
                af[i]  = *(const short8*)(&Hh[(wm + i * 16 + lr) * 136 + k0 + lk]);
                alf[i] = *(const short8*)(&Hl[(wm + i * 16 + lr) * 136 + k0 + lk]);
                wf[i]  = *(const short8*)(&Wh[(wn + i * 16 + lr) * 40 + lk]);
                wlf[i] = *(const short8*)(&Wl[(wn + i * 16 + lr) * 40 + lk]);
            }
            #pragma unroll
            for (int i = 0; i < 4; ++i)
                #pragma unroll
                for (int j = 0; j < 4; ++j) {
                    acc[i][j] = __builtin_amdgcn_mfma_f32_16x16x32_bf16(
                        af[i], wf[j], acc[i][j], 0, 0, 0);
                    acc[i][j] = __builtin_amdgcn_mfma_f32_16x16x32_bf16(
                        af[i], wlf[j], acc[i][j], 0, 0, 0);
                    acc[i][j] = __builtin_amdgcn_mfma_f32_16x16x32_bf16(
                        alf[i], wf[j], acc[i][j], 0, 0, 0);
                }
        }
        #pragma unroll
        for (int i = 0; i < 4; ++i)
            #pragma unroll
            for (int r = 0; r < 4; ++r) {
                int m = m0 + wm + i * 16 + quad * 4 + r;
                if (m >= M) continue;
                #pragma unroll
                for (int j = 0; j < 4; ++j) {
                    int n = nt * 128 + wn + j * 16 + lr;
                    float x = acc[i][j][r] + b2[n];
                    if (out_b) out_b[(long)m * 512 + (long)(n & 127) * 4 + nt] = f2b(x);
                    else       out_f[(long)m * 384 + n] = x;
                }
            }
    }
}

// ---------------------------------------------------------------------------
// Pre-split MFMA GEMM (UV only): dual weights, fp32 C0/C1 routing by n-tile.
// ---------------------------------------------------------------------------
__global__ __launch_bounds__(256) void gemm_ps_kernel(
    const ushort_t* __restrict__ Ahg, const ushort_t* __restrict__ Alg,
    const ushort_t* __restrict__ Whi, const ushort_t* __restrict__ Wlo,
    const ushort_t* __restrict__ W2h, const ushort_t* __restrict__ W2l,
    float* __restrict__ C0, float* __restrict__ C1,
    int M, int K)
{
    __shared__ __align__(16) ushort_t Ah[128 * 40];
    __shared__ __align__(16) ushort_t Al[128 * 40];
    __shared__ __align__(16) ushort_t Wh[128 * 40];
    __shared__ __align__(16) ushort_t Wl[128 * 40];
    const int t    = threadIdx.x;
    const int m0   = blockIdx.x * 128;
    const int nt   = blockIdx.y;          // 0 -> U/C0, 1 -> V/C1
    const int wv   = t >> 6;
    const int lane = t & 63;
    const int wm   = (wv >> 1) * 64;
    const int wn   = (wv & 1) * 64;
    const int lr   = lane & 15;
    const int lk   = (lane >> 4) * 8;
    const int srow = t >> 2;
    const int scol = (t & 3) * 8;
    const ushort_t* Wsh = nt ? W2h : Whi;
    const ushort_t* Wsl = nt ? W2l : Wlo;

    floatx4 acc[4][4] = {};

    for (int k0 = 0; k0 < K; k0 += 32) {
        #pragma unroll
        for (int h = 0; h < 2; ++h) {
            int r = srow + h * 64;
            int m = m0 + r; if (m >= M) m = M - 1;
            *(uint4*)(&Ah[r * 40 + scol]) =
                *(const uint4*)(Ahg + (long)m * K + k0 + scol);
            *(uint4*)(&Al[r * 40 + scol]) =
                *(const uint4*)(Alg + (long)m * K + k0 + scol);
            *(uint4*)(&Wh[r * 40 + scol]) =
                *(const uint4*)(Wsh + (long)r * K + k0 + scol);
            *(uint4*)(&Wl[r * 40 + scol]) =
                *(const uint4*)(Wsl + (long)r * K + k0 + scol);
        }
        __syncthreads();
        short8 ah[4], al[4], wh[4], wl[4];
        #pragma unroll
        for (int i = 0; i < 4; ++i) {
            ah[i] = *(const short8*)(&Ah[(wm + i * 16 + lr) * 40 + lk]);
            al[i] = *(const short8*)(&Al[(wm + i * 16 + lr) * 40 + lk]);
            wh[i] = *(const short8*)(&Wh[(wn + i * 16 + lr) * 40 + lk]);
            wl[i] = *(const short8*)(&Wl[(wn + i * 16 + lr) * 40 + lk]);
        }
        #pragma unroll
        for (int i = 0; i < 4; ++i)
            #pragma unroll
            for (int j = 0; j < 4; ++j) {
                acc[i][j] = __builtin_amdgcn_mfma_f32_16x16x32_bf16(
                    ah[i], wh[j], acc[i][j], 0, 0, 0);
                acc[i][j] = __builtin_amdgcn_mfma_f32_16x16x32_bf16(
                    ah[i], wl[j], acc[i][j], 0, 0, 0);
                acc[i][j] = __builtin_amdgcn_mfma_f32_16x16x32_bf16(
                    al[i], wh[j], acc[i][j], 0, 0, 0);
            }
        __syncthreads();
    }

    float* C = nt ? C1 : C0;
    #pragma unroll
    for (int i = 0; i < 4; ++i)
        #pragma unroll
        for (int r = 0; r < 4; ++r) {
            int m = m0 + wm + i * 16 + (lane >> 4) * 4 + r;
            if (m >= M) continue;
            #pragma unroll
            for (int j = 0; j < 4; ++j) {
                int n = wn + j * 16 + lr;
                C[(long)m * 128 + n] = acc[i][j][r];
            }
        }
}

// ---------------------------------------------------------------------------
__global__ __launch_bounds__(256) void split_kernel(
    const float* __restrict__ src, ushort_t* __restrict__ hi,
    ushort_t* __restrict__ lo, int n)
{
    int i = blockIdx.x * blockDim.x + threadIdx.x;
    if (i >= n) return;
    float x = src[i];
    unsigned short h = f2b(x);
    hi[i] = h;
    lo[i] = f2b(x - b2f(h));
}

// ---------------------------------------------------------------------------
// dist_W transpose: dW [NCONV][3*128][20]  ->  dWt [NCONV][3][5][128][4]
// so edge_aggr can stage it to LDS and read stride-16B conflict-free b128.
// ---------------------------------------------------------------------------
__global__ __launch_bounds__(256) void transpose_dw_kernel(
    const float* __restrict__ dW, float* __restrict__ dWt, int total)
{
    int idx = blockIdx.x * blockDim.x + threadIdx.x;
    if (idx >= total) return;
    int kk = idx & 3;
    int f  = (idx >> 2) & 127;
    int k4 = (idx >> 9) % 5;
    int c  = (idx / (4 * 128 * 5)) % 3;
    int l  = idx / (4 * 128 * 5 * 3);
    int k  = k4 * 4 + kk;
    dWt[idx] = dW[((long)(l * 3 + c) * 128 + f) * NRBF + k];
}

// ---------------------------------------------------------------------------
// CSR build
// ---------------------------------------------------------------------------
__global__ __launch_bounds__(256) void hist_kernel(
    const int* __restrict__ nbr, int* __restrict__ deg, int Ed)
{
    int e = blockIdx.x * blockDim.x + threadIdx.x;
    if (e >= Ed) return;
    int E = Ed >> 1;
    int i = (e < E) ? nbr[2 * e] : nbr[2 * (e - E) + 1];
    atomicAdd(&deg[i], 1);
}

__device__ inline int wave_incl_scan(int x, int lane)
{
    #pragma unroll
    for (int s = 1; s < 64; s <<= 1) {
        int y = __shfl_up(x, s, 64);
        if (lane >= s) x += y;
    }
    return x;
}

__global__ __launch_bounds__(1024) void scan_kernel(
    const int* __restrict__ deg, int* __restrict__ off,
    int* __restrict__ cursor, int N)
{
    __shared__ int wsum[16];
    __shared__ int carry_s;
    const int t = threadIdx.x;
    const int lane = t & 63;
    const int w = t >> 6;
    if (t == 0) { carry_s = 0; off[0] = 0; }
    __syncthreads();
    for (int base = 0; base < N; base += 1024) {
        int i = base + t;
        int x = (i < N) ? deg[i] : 0;
        int sc = wave_incl_scan(x, lane);
        if (lane == 63) wsum[w] = sc;
        __syncthreads();
        if (w == 0) {
            int v = (lane < 16) ? wsum[lane] : 0;
            int vs = wave_incl_scan(v, lane);
            if (lane < 16) wsum[lane] = vs;
        }
        __syncthreads();
        int waveoff = (w > 0) ? wsum[w - 1] : 0;
        int inc = sc + waveoff + carry_s;
        if (i < N) { off[i + 1] = inc; cursor[i] = inc - x; }
        __syncthreads();
        if (t == 1023) carry_s = inc;
        __syncthreads();
    }
}

__global__ __launch_bounds__(256) void scatter_geom_kernel(
    const int* __restrict__ nbr, const float* __restrict__ xyz,
    int* __restrict__ cursor, int* __restrict__ csr_j,
    float* __restrict__ csr_geo, float* __restrict__ csr_rbfe, int Ed)
{
    int e = blockIdx.x * blockDim.x + threadIdx.x;
    if (e >= Ed) return;
    int E = Ed >> 1;
    int i, j;
    if (e < E) { i = nbr[2 * e];         j = nbr[2 * e + 1]; }
    else       { int u = e - E; i = nbr[2 * u + 1]; j = nbr[2 * u]; }

    int p = atomicAdd(&cursor[i], 1);
    csr_j[p] = j;

    float rx = xyz[3 * j + 0] - xyz[3 * i + 0];
    float ry = xyz[3 * j + 1] - xyz[3 * i + 1];
    float rz = xyz[3 * j + 2] - xyz[3 * i + 2];
    float d   = sqrtf(rx * rx + ry * ry + rz * rz);
    float inv = 1.f / d;
    float ev = (d < 20.f) ? 0.5f * (__cosf(PI_F * d / 20.f) + 1.f) : 0.f;
    ((float4*)csr_geo)[p] = make_float4(rx * inv, ry * inv, rz * inv, ev);
    float base = PI_F * d / 20.f;
    #pragma unroll
    for (int k = 0; k < NRBF; ++k)
        csr_rbfe[(long)p * NRBF + k] = ev * __sinf((float)(k + 1) * base) * inv;
}

// ---------------------------------------------------------------------------
// Edge aggregation v2:
//  - dist coefficients pre-transposed -> LDS (30KB), stride-16B b128 reads
//    (fixes VGPR-starved strided re-loads of distW in the old version)
//  - phi gathered as ONE ushort4 (packed [j][128][4] bf16)
//  - v gathered as ONE float4 (packed [j][128][4] fp32)
//  - gathers software-pipelined one edge ahead
//  - 4 nodes per 512-thread block share one LDS coefficient copy
// ---------------------------------------------------------------------------
__global__ __launch_bounds__(512) void edge_aggr_kernel(
    const int* __restrict__ off, const int* __restrict__ csr_j,
    const float* __restrict__ csr_geo, const float* __restrict__ csr_rbfe,
    const float* __restrict__ dWt, const float* __restrict__ distb,
    const ushort_t* __restrict__ phib, const float* __restrict__ vold,
    float* __restrict__ s, float* __restrict__ vnew,
    ushort_t* __restrict__ vnh, ushort_t* __restrict__ vnl, int N, int SP)
{
    __shared__ __align__(16) float wco[3 * 5 * 128 * 4];   // 30720 B

    const int t = threadIdx.x;
    for (int idx = t; idx < 3 * 5 * 128; idx += 512)
        ((float4*)wco)[idx] = ((const float4*)dWt)[idx];
    __syncthreads();

    const int f   = t & 127;
    const int sub = __builtin_amdgcn_readfirstlane(t >> 7);   // wave-uniform
    const float b0 = distb[f];
    const float b1 = distb[128 + f];
    const float b2 = distb[256 + f];

    const ushort4* __restrict__ phi4 = (const ushort4*)phib;
    const float4*  __restrict__ v4   = (const float4*)vold;
    const float4*  __restrict__ geo4 = (const float4*)csr_geo;

    for (int node = blockIdx.x * 4 + sub; node < N; node += gridDim.x * 4) {
        const int p0 = off[node], p1 = off[node + 1];
        float ssum = 0.f, v0 = 0.f, v1 = 0.f, v2 = 0.f;

        ushort4 phn = make_ushort4(0, 0, 0, 0);
        float4  vjn = make_float4(0.f, 0.f, 0.f, 0.f);
        if (p0 < p1) {
            long q = (long)csr_j[p0] * 128 + f;
            phn = phi4[q];
            vjn = v4[q];
        }
        for (int p = p0; p < p1; ++p) {
            ushort4 ph = phn;
            float4  vj = vjn;
            if (p + 1 < p1) {                       // prefetch next gathers
                long q = (long)csr_j[p + 1] * 128 + f;
                phn = phi4[q];
                vjn = v4[q];
            }
            float4 ge = geo4[p];                    // {ux,uy,uz,env}, uniform
            const float* rb = csr_rbfe + (long)p * NRBF;
            float w0 = ge.w * b0, w1 = ge.w * b1, w2 = ge.w * b2;
            #pragma unroll
            for (int k4 = 0; k4 < 5; ++k4) {
                float4 rv = *(const float4*)(rb + k4 * 4);
                float4 c0 = *(const float4*)(&wco[(0 * 5 + k4) * 512 + f * 4]);
                float4 c1 = *(const float4*)(&wco[(1 * 5 + k4) * 512 + f * 4]);
                float4 c2 = *(const float4*)(&wco[(2 * 5 + k4) * 512 + f * 4]);
                w0 += rv.x * c0.x + rv.y * c0.y + rv.z * c0.z + rv.w * c0.w;
                w1 += rv.x * c1.x + rv.y * c1.y + rv.z * c1.z + rv.w * c1.w;
                w2 += rv.x * c2.x + rv.y * c2.y + rv.z * c2.z + rv.w * c2.w;
            }
            float i0 = b2f(ph.x) * w0;
            float i1 = b2f(ph.y) * w1;
            float i2 = b2f(ph.z) * w2;
            ssum += i1;
            v0 += i2 * ge.x + i0 * vj.x;
            v1 += i2 * ge.y + i0 * vj.y;
            v2 += i2 * ge.z + i0 * vj.z;
        }
        long iv = (long)node * FEAT + f;
        s[iv] += ssum;
        float4 vc = v4[iv];
        float n0 = vc.x + v0;
        float n1 = vc.y + v1;
        float n2 = vc.z + v2;
        ((float4*)vnew)[iv] = make_float4(n0, n1, n2, 0.f);
        unsigned short h0 = f2b(n0), h1 = f2b(n1), h2 = f2b(n2);
        vnh[iv]          = h0;  vnl[iv]          = f2b(n0 - b2f(h0));
        vnh[SP + iv]     = h1;  vnl[SP + iv]     = f2b(n1 - b2f(h1));
        vnh[2 * SP + iv] = h2;  vnl[2 * SP + iv] = f2b(n2 - b2f(h2));
    }
}

// ---------------------------------------------------------------------------
// Elementwise kernels
// ---------------------------------------------------------------------------
__global__ __launch_bounds__(256) void init_s_kernel(
    const float* __restrict__ cg_s, float* __restrict__ s,
    float* __restrict__ vA, int nS, int nV)
{
    int idx = blockIdx.x * blockDim.x + threadIdx.x;
    if (idx < nS) s[idx] = cg_s[idx];
    if (idx < nV) vA[idx] = 0.f;
}

// final: if outv != null, v result goes interleaved to outv (and v not written)
// v / vnew are PACKED float4 [idx][4] now.
__global__ __launch_bounds__(256) void update_sv_kernel(
    float* __restrict__ s, float* __restrict__ v,
    const float* __restrict__ uv, const float* __restrict__ vv,
    const float* __restrict__ a, float* __restrict__ outv, int SP)
{
    int idx = blockIdx.x * blockDim.x + threadIdx.x;
    if (idx >= SP) return;
    int n = idx >> 7, g = idx & 127;
    float u0 = uv[idx], u1 = uv[SP + idx], u2 = uv[2 * SP + idx];
    float w0 = vv[idx], w1 = vv[SP + idx], w2 = vv[2 * SP + idx];
    long ab = (long)n * 384;
    float dot = u0 * w0 + u1 * w1 + u2 * w2;
    s[idx] += dot * a[ab + 128 + g] + a[ab + 256 + g];
    float g0 = a[ab + g];
    float4 xv = ((const float4*)v)[idx];
    float x0 = xv.x + u0 * g0;
    float x1 = xv.y + u1 * g0;
    float x2 = xv.z + u2 * g0;
    if (outv) {
        outv[(long)idx * 3 + 0] = x0;
        outv[(long)idx * 3 + 1] = x1;
        outv[(long)idx * 3 + 2] = x2;
    } else {
        ((float4*)v)[idx] = make_float4(x0, x1, x2, 0.f);
    }
}

// ---------------------------------------------------------------------------
extern "C" void kernel_launch(void* const* d_in, const int* in_sizes, int n_in,
                              void* d_out, int out_size, void* d_ws, size_t ws_size,
                              hipStream_t stream)
{
    const float* xyz     = (const float*)d_in[0];
    const int*   nbr     = (const int*)  d_in[1];
    const float* cg_s    = (const float*)d_in[2];
    const float* msg_W1  = (const float*)d_in[3];
    const float* msg_b1  = (const float*)d_in[4];
    const float* msg_W2  = (const float*)d_in[5];
    const float* msg_b2  = (const float*)d_in[6];
    const float* dist_W  = (const float*)d_in[7];
    const float* dist_b  = (const float*)d_in[8];
    const float* upd_U   = (const float*)d_in[9];
    const float* upd_V   = (const float*)d_in[10];
    const float* upd_sW1 = (const float*)d_in[11];
    const float* upd_sb1 = (const float*)d_in[12];
    const float* upd_sW2 = (const float*)d_in[13];
    const float* upd_sb2 = (const float*)d_in[14];

    const int E  = in_sizes[1] / 2;
    const int Ed = 2 * E;
    const int N  = in_sizes[2] / FEAT;
    const int SP = N * FEAT;

    float* s    = (float*)d_out;
    float* outv = (float*)d_out + (long)SP;

    // workspace carve-up
    float* w = (float*)d_ws;
    size_t off_ = 0;
    auto alloc = [&](size_t nelem) {
        float* p = w + off_;
        off_ += (nelem + 255) & ~(size_t)255;
        return p;
    };
    auto allocb = [&](size_t nelem) {
        return (ushort_t*)alloc((nelem + 1) / 2);
    };
    int*   deg      = (int*)alloc((size_t)N);
    int*   off      = (int*)alloc((size_t)N + 1);
    int*   cursor   = (int*)alloc((size_t)N);
    int*   csr_j    = (int*)alloc((size_t)Ed);
    float* csr_geo  = alloc((size_t)Ed * 4);
    float* csr_rbfe = alloc((size_t)Ed * NRBF);
    float* a_buf    = alloc((size_t)N * 384);
    float* u_v      = alloc((size_t)3 * SP);
    float* v_v      = alloc((size_t)3 * SP);
    float* vA       = alloc((size_t)4 * SP);   // packed [idx][4]
    float* vB       = alloc((size_t)4 * SP);   // packed [idx][4]
    float* dWt      = alloc((size_t)NCONV * 3 * NRBF * FEAT);
    ushort_t* phi_b = allocb((size_t)N * 512); // packed [m][128][4]
    ushort_t* vnh   = allocb((size_t)3 * SP);
    ushort_t* vnl   = allocb((size_t)3 * SP);
    const int n1 = NCONV * FEAT * FEAT;
    const int n2 = NCONV * 3 * FEAT * FEAT;
    const int n3 = NCONV * FEAT * 2 * FEAT;
    ushort_t* w1h  = allocb((size_t)n1);
    ushort_t* w1l  = allocb((size_t)n1);
    ushort_t* w2h  = allocb((size_t)n2);
    ushort_t* w2l  = allocb((size_t)n2);
    ushort_t* uh   = allocb((size_t)n1);
    ushort_t* ul   = allocb((size_t)n1);
    ushort_t* vh   = allocb((size_t)n1);
    ushort_t* vl   = allocb((size_t)n1);
    ushort_t* sw1h = allocb((size_t)n3);
    ushort_t* sw1l = allocb((size_t)n3);
    ushort_t* sw2h = allocb((size_t)n2);
    ushort_t* sw2l = allocb((size_t)n2);
    (void)ws_size; (void)n_in; (void)out_size;

    // weight split (once per launch)
    split_kernel<<<(n1 + 255) / 256, 256, 0, stream>>>(msg_W1, w1h, w1l, n1);
    split_kernel<<<(n2 + 255) / 256, 256, 0, stream>>>(msg_W2, w2h, w2l, n2);
    split_kernel<<<(n1 + 255) / 256, 256, 0, stream>>>(upd_U, uh, ul, n1);
    split_kernel<<<(n1 + 255) / 256, 256, 0, stream>>>(upd_V, vh, vl, n1);
    split_kernel<<<(n3 + 255) / 256, 256, 0, stream>>>(upd_sW1, sw1h, sw1l, n3);
    split_kernel<<<(n2 + 255) / 256, 256, 0, stream>>>(upd_sW2, sw2h, sw2l, n2);

    // dist_W transpose (once per launch, all layers)
    {
        int total = NCONV * 3 * NRBF * FEAT;
        transpose_dw_kernel<<<(total + 255) / 256, 256, 0, stream>>>(
            dist_W, dWt, total);
    }

    // init s <- cg_s, vA <- 0 (packed size)
    {
        int n = 4 * SP;
        init_s_kernel<<<(n + 255) / 256, 256, 0, stream>>>(cg_s, s, vA, SP, n);
    }

    // CSR build (once per launch)
    hipMemsetAsync(deg, 0, (size_t)N * sizeof(int), stream);
    hist_kernel<<<(Ed + 255) / 256, 256, 0, stream>>>(nbr, deg, Ed);
    scan_kernel<<<1, 1024, 0, stream>>>(deg, off, cursor, N);
    scatter_geom_kernel<<<(Ed + 255) / 256, 256, 0, stream>>>(
        nbr, xyz, cursor, csr_j, csr_geo, csr_rbfe, Ed);

    float* vold = vA;
    float* vnew = vB;
    dim3 gM((N + 127) / 128, 1);
    dim3 gUV((3 * N + 127) / 128, 2);

    for (int l = 0; l < NCONV; ++l) {
        const float* b1  = msg_b1  + (long)l * FEAT;
        const float* b2  = msg_b2  + (long)l * 3 * FEAT;
        const float* db  = dist_b  + (long)l * 3 * FEAT;
        const float* sb1 = upd_sb1 + (long)l * FEAT;
        const float* sb2 = upd_sb2 + (long)l * 3 * FEAT;
        const long o1 = (long)l * FEAT * FEAT;
        const long o2 = (long)l * 3 * FEAT * FEAT;
        const long o3 = (long)l * FEAT * 2 * FEAT;

        // fused phi-MLP: s -> (h in LDS) -> phi_b (packed bf16 hi)
        mlp_fused_kernel<<<gM, 256, 0, stream>>>(
            s, nullptr, w1h + o1, w1l + o1, b1, w2h + o2, w2l + o2, b2,
            phi_b, nullptr, N, FEAT, SP);

        // atomic-free message aggregation (v2)
        edge_aggr_kernel<<<(N + 3) / 4, 512, 0, stream>>>(
            off, csr_j, csr_geo, csr_rbfe, dWt + (long)l * 3 * NRBF * FEAT, db,
            phi_b, vold, s, vnew, vnh, vnl, N, SP);

        // u_v / v_v in one dispatch (y=0 -> U, y=1 -> V)
        gemm_ps_kernel<<<gUV, 256, 0, stream>>>(
            vnh, vnl, uh + o1, ul + o1, vh + o1, vl + o1,
            u_v, v_v, 3 * N, FEAT);

        // fused gate-MLP: [s | norm(v_v)] -> (h in LDS) -> a_buf (fp32)
        mlp_fused_kernel<<<gM, 256, 0, stream>>>(
            s, v_v, sw1h + o3, sw1l + o3, sb1, sw2h + o2, sw2l + o2, sb2,
            nullptr, a_buf, N, 2 * FEAT, SP);

        // final update; last layer writes v interleaved straight to output
        float* ov = (l == NCONV - 1) ? outv : nullptr;
        update_sv_kernel<<<(SP + 255) / 256, 256, 0, stream>>>(
            s, vnew, u_v, v_v, a_buf, ov, SP);

        float* tmp = vold; vold = vnew; vnew = tmp;
    }
}

// Round 3
// 1036.736 us; speedup vs baseline: 1.0595x; 1.0595x over previous
//
#include <hip/hip_runtime.h>
#include <math.h>

#define FEAT 128
#define NRBF 20
#define NCONV 3
#define PI_F 3.14159265358979323846f

typedef __attribute__((ext_vector_type(8))) short short8;
typedef __attribute__((ext_vector_type(4))) float floatx4;
typedef unsigned short ushort_t;

__device__ inline float b2f(unsigned short u) {
    union { unsigned int i; float f; } c; c.i = ((unsigned int)u) << 16; return c.f;
}
__device__ inline unsigned short f2b(float x) {
    union { float f; unsigned int i; } c; c.f = x;
    unsigned int u = c.i;
    return (unsigned short)((u + 0x7fffu + ((u >> 16) & 1u)) >> 16);
}
__device__ inline float u2f(unsigned int u) {
    union { unsigned int i; float f; } c; c.i = u; return c.f;
}
__device__ inline unsigned int f2u(float x) {
    union { float f; unsigned int i; } c; c.f = x; return c.i;
}

// ---------------------------------------------------------------------------
// Fused 2-layer MLP: out[M,384] = silu(A1 @ W1^T + b1) @ W2^T + b2
// A1 = s[M,128] (phi mode) or [s | norm(vv)] [M,256] (gate mode, vv != null).
// phi mode writes the PACKED gather buffer cgA: out_b[m*512 + g*4 + c]
// (g=n&127, c=n>>7) -> cgA.xyz = phi chunks; cgA.w (v hi16) is NOT touched.
// ---------------------------------------------------------------------------
__global__ __launch_bounds__(256) void mlp_fused_kernel(
    const float* __restrict__ s, const float* __restrict__ vv,
    const ushort_t* __restrict__ W1h, const ushort_t* __restrict__ W1l,
    const float* __restrict__ b1,
    const ushort_t* __restrict__ W2h, const ushort_t* __restrict__ W2l,
    const float* __restrict__ b2,
    ushort_t* __restrict__ out_b, float* __restrict__ out_f,
    int M, int K1, int SP)
{
    __shared__ __align__(16) ushort_t Ah[128 * 40];
    __shared__ __align__(16) ushort_t Al[128 * 40];
    __shared__ __align__(16) ushort_t Wh[128 * 40];
    __shared__ __align__(16) ushort_t Wl[128 * 40];
    __shared__ __align__(16) ushort_t Hh[128 * 136];
    __shared__ __align__(16) ushort_t Hl[128 * 136];

    const int t    = threadIdx.x;
    const int m0   = blockIdx.x * 128;
    const int wv   = t >> 6;
    const int lane = t & 63;
    const int wm   = (wv >> 1) * 64;
    const int wn   = (wv & 1) * 64;
    const int lr   = lane & 15;
    const int lk   = (lane >> 4) * 8;
    const int quad = lane >> 4;
    const int arow = t >> 3;          // 0..31, 4 passes of 32 rows
    const int acol = (t & 7) * 4;     // fp32 x4
    const int wrow = t >> 2;          // 0..63, 2 passes of 64 rows
    const int wcol = (t & 3) * 8;     // ushort x8

    floatx4 acc[4][4] = {};

    // ---- stage 1: h = silu(A1 @ W1^T + b1) ----
    for (int k0 = 0; k0 < K1; k0 += 32) {
        #pragma unroll
        for (int h = 0; h < 4; ++h) {
            int r = arow + h * 32;
            int m = m0 + r; if (m >= M) m = M - 1;   // clamp tail
            float xs[4];
            if (k0 < 128) {
                float4 av = *(const float4*)(s + (long)m * 128 + k0 + acol);
                xs[0] = av.x; xs[1] = av.y; xs[2] = av.z; xs[3] = av.w;
            } else {
                long base = (long)m * 128 + (k0 - 128 + acol);
                float4 a0 = *(const float4*)(vv + base);
                float4 a1 = *(const float4*)(vv + (long)SP + base);
                float4 a2 = *(const float4*)(vv + 2 * (long)SP + base);
                xs[0] = sqrtf(a0.x * a0.x + a1.x * a1.x + a2.x * a2.x);
                xs[1] = sqrtf(a0.y * a0.y + a1.y * a1.y + a2.y * a2.y);
                xs[2] = sqrtf(a0.z * a0.z + a1.z * a1.z + a2.z * a2.z);
                xs[3] = sqrtf(a0.w * a0.w + a1.w * a1.w + a2.w * a2.w);
            }
            unsigned short hh[4], ll[4];
            #pragma unroll
            for (int q = 0; q < 4; ++q) {
                hh[q] = f2b(xs[q]);
                ll[q] = f2b(xs[q] - b2f(hh[q]));
            }
            *(ushort4*)(&Ah[r * 40 + acol]) = make_ushort4(hh[0], hh[1], hh[2], hh[3]);
            *(ushort4*)(&Al[r * 40 + acol]) = make_ushort4(ll[0], ll[1], ll[2], ll[3]);
        }
        #pragma unroll
        for (int h = 0; h < 2; ++h) {
            int r = wrow + h * 64;
            *(uint4*)(&Wh[r * 40 + wcol]) =
                *(const uint4*)(W1h + (long)r * K1 + k0 + wcol);
            *(uint4*)(&Wl[r * 40 + wcol]) =
                *(const uint4*)(W1l + (long)r * K1 + k0 + wcol);
        }
        __syncthreads();
        short8 af[4], alf[4], wf[4], wlf[4];
        #pragma unroll
        for (int i = 0; i < 4; ++i) {
            af[i]  = *(const short8*)(&Ah[(wm + i * 16 + lr) * 40 + lk]);
            alf[i] = *(const short8*)(&Al[(wm + i * 16 + lr) * 40 + lk]);
            wf[i]  = *(const short8*)(&Wh[(wn + i * 16 + lr) * 40 + lk]);
            wlf[i] = *(const short8*)(&Wl[(wn + i * 16 + lr) * 40 + lk]);
        }
        #pragma unroll
        for (int i = 0; i < 4; ++i)
            #pragma unroll
            for (int j = 0; j < 4; ++j) {
                acc[i][j] = __builtin_amdgcn_mfma_f32_16x16x32_bf16(
                    af[i], wf[j], acc[i][j], 0, 0, 0);
                acc[i][j] = __builtin_amdgcn_mfma_f32_16x16x32_bf16(
                    af[i], wlf[j], acc[i][j], 0, 0, 0);
                acc[i][j] = __builtin_amdgcn_mfma_f32_16x16x32_bf16(
                    alf[i], wf[j], acc[i][j], 0, 0, 0);
            }
        __syncthreads();
    }

    // stage-1 epilogue -> h in LDS (hi/lo), C/D layout col=lane&15, row=quad*4+r
    #pragma unroll
    for (int i = 0; i < 4; ++i)
        #pragma unroll
        for (int r = 0; r < 4; ++r) {
            int mrow = wm + i * 16 + quad * 4 + r;
            #pragma unroll
            for (int j = 0; j < 4; ++j) {
                int kcol = wn + j * 16 + lr;
                float x = acc[i][j][r] + b1[kcol];
                x *= 1.f / (1.f + __expf(-x));
                unsigned short hh = f2b(x);
                Hh[mrow * 136 + kcol] = hh;
                Hl[mrow * 136 + kcol] = f2b(x - b2f(hh));
            }
        }

    // ---- stage 2: out = h @ W2^T + b2, 3 n-tiles of 128 ----
    for (int nt = 0; nt < 3; ++nt) {
        #pragma unroll
        for (int i = 0; i < 4; ++i)
            #pragma unroll
            for (int j = 0; j < 4; ++j)
                #pragma unroll
                for (int q = 0; q < 4; ++q) acc[i][j][q] = 0.f;
        for (int k0 = 0; k0 < 128; k0 += 32) {
            __syncthreads();   // guard Wh/Wl overwrite (and H writes on 1st pass)
            #pragma unroll
            for (int h = 0; h < 2; ++h) {
                int r = wrow + h * 64;
                long wo = (long)(nt * 128 + r) * 128;
                *(uint4*)(&Wh[r * 40 + wcol]) = *(const uint4*)(W2h + wo + k0 + wcol);
                *(uint4*)(&Wl[r * 40 + wcol]) = *(const uint4*)(W2l + wo + k0 + wcol);
            }
            __syncthreads();
            short8 af[4], alf[4], wf[4], wlf[4];
            #pragma unroll
            for (int i = 0; i < 4; ++i) {
                af[i]  = *(const short8*)(&Hh[(wm + i * 16 + lr) * 136 + k0 + lk]);
                alf[i] = *(const short8*)(&Hl[(wm + i * 16 + lr) * 136 + k0 + lk]);
                wf[i]  = *(const short8*)(&Wh[(wn + i * 16 + lr) * 40 + lk]);
                wlf[i] = *(const short8*)(&Wl[(wn + i * 16 + lr) * 40 + lk]);
            }
            #pragma unroll
            for (int i = 0; i < 4; ++i)
                #pragma unroll
                for (int j = 0; j < 4; ++j) {
                    acc[i][j] = __builtin_amdgcn_mfma_f32_16x16x32_bf16(
                        af[i], wf[j], acc[i][j], 0, 0, 0);
                    acc[i][j] = __builtin_amdgcn_mfma_f32_16x16x32_bf16(
                        af[i], wlf[j], acc[i][j], 0, 0, 0);
                    acc[i][j] = __builtin_amdgcn_mfma_f32_16x16x32_bf16(
                        alf[i], wf[j], acc[i][j], 0, 0, 0);
                }
        }
        #pragma unroll
        for (int i = 0; i < 4; ++i)
            #pragma unroll
            for (int r = 0; r < 4; ++r) {
                int m = m0 + wm + i * 16 + quad * 4 + r;
                if (m >= M) continue;
                #pragma unroll
                for (int j = 0; j < 4; ++j) {
                    int n = nt * 128 + wn + j * 16 + lr;
                    float x = acc[i][j][r] + b2[n];
                    if (out_b) out_b[(long)m * 512 + (long)(n & 127) * 4 + nt] = f2b(x);
                    else       out_f[(long)m * 384 + n] = x;
                }
            }
    }
}

// ---------------------------------------------------------------------------
// Pre-split MFMA GEMM (UV only): dual weights, fp32 C0/C1 routing by n-tile.
// ---------------------------------------------------------------------------
__global__ __launch_bounds__(256) void gemm_ps_kernel(
    const ushort_t* __restrict__ Ahg, const ushort_t* __restrict__ Alg,
    const ushort_t* __restrict__ Whi, const ushort_t* __restrict__ Wlo,
    const ushort_t* __restrict__ W2h, const ushort_t* __restrict__ W2l,
    float* __restrict__ C0, float* __restrict__ C1,
    int M, int K)
{
    __shared__ __align__(16) ushort_t Ah[128 * 40];
    __shared__ __align__(16) ushort_t Al[128 * 40];
    __shared__ __align__(16) ushort_t Wh[128 * 40];
    __shared__ __align__(16) ushort_t Wl[128 * 40];
    const int t    = threadIdx.x;
    const int m0   = blockIdx.x * 128;
    const int nt   = blockIdx.y;          // 0 -> U/C0, 1 -> V/C1
    const int wv   = t >> 6;
    const int lane = t & 63;
    const int wm   = (wv >> 1) * 64;
    const int wn   = (wv & 1) * 64;
    const int lr   = lane & 15;
    const int lk   = (lane >> 4) * 8;
    const int srow = t >> 2;
    const int scol = (t & 3) * 8;
    const ushort_t* Wsh = nt ? W2h : Whi;
    const ushort_t* Wsl = nt ? W2l : Wlo;

    floatx4 acc[4][4] = {};

    for (int k0 = 0; k0 < K; k0 += 32) {
        #pragma unroll
        for (int h = 0; h < 2; ++h) {
            int r = srow + h * 64;
            int m = m0 + r; if (m >= M) m = M - 1;
            *(uint4*)(&Ah[r * 40 + scol]) =
                *(const uint4*)(Ahg + (long)m * K + k0 + scol);
            *(uint4*)(&Al[r * 40 + scol]) =
                *(const uint4*)(Alg + (long)m * K + k0 + scol);
            *(uint4*)(&Wh[r * 40 + scol]) =
                *(const uint4*)(Wsh + (long)r * K + k0 + scol);
            *(uint4*)(&Wl[r * 40 + scol]) =
                *(const uint4*)(Wsl + (long)r * K + k0 + scol);
        }
        __syncthreads();
        short8 ah[4], al[4], wh[4], wl[4];
        #pragma unroll
        for (int i = 0; i < 4; ++i) {
            ah[i] = *(const short8*)(&Ah[(wm + i * 16 + lr) * 40 + lk]);
            al[i] = *(const short8*)(&Al[(wm + i * 16 + lr) * 40 + lk]);
            wh[i] = *(const short8*)(&Wh[(wn + i * 16 + lr) * 40 + lk]);
            wl[i] = *(const short8*)(&Wl[(wn + i * 16 + lr) * 40 + lk]);
        }
        #pragma unroll
        for (int i = 0; i < 4; ++i)
            #pragma unroll
            for (int j = 0; j < 4; ++j) {
                acc[i][j] = __builtin_amdgcn_mfma_f32_16x16x32_bf16(
                    ah[i], wh[j], acc[i][j], 0, 0, 0);
                acc[i][j] = __builtin_amdgcn_mfma_f32_16x16x32_bf16(
                    ah[i], wl[j], acc[i][j], 0, 0, 0);
                acc[i][j] = __builtin_amdgcn_mfma_f32_16x16x32_bf16(
                    al[i], wh[j], acc[i][j], 0, 0, 0);
            }
        __syncthreads();
    }

    float* C = nt ? C1 : C0;
    #pragma unroll
    for (int i = 0; i < 4; ++i)
        #pragma unroll
        for (int r = 0; r < 4; ++r) {
            int m = m0 + wm + i * 16 + (lane >> 4) * 4 + r;
            if (m >= M) continue;
            #pragma unroll
            for (int j = 0; j < 4; ++j) {
                int n = wn + j * 16 + lr;
                C[(long)m * 128 + n] = acc[i][j][r];
            }
        }
}

// ---------------------------------------------------------------------------
__global__ __launch_bounds__(256) void split_kernel(
    const float* __restrict__ src, ushort_t* __restrict__ hi,
    ushort_t* __restrict__ lo, int n)
{
    int i = blockIdx.x * blockDim.x + threadIdx.x;
    if (i >= n) return;
    float x = src[i];
    unsigned short h = f2b(x);
    hi[i] = h;
    lo[i] = f2b(x - b2f(h));
}

// ---------------------------------------------------------------------------
// dist_W transpose: dW [NCONV][3*128][20]  ->  dWt [NCONV][3][5][128][4]
// so edge_aggr lanes can preload their 60 coefficients with 15 coalesced
// float4 loads (once per persistent block).
// ---------------------------------------------------------------------------
__global__ __launch_bounds__(256) void transpose_dw_kernel(
    const float* __restrict__ dW, float* __restrict__ dWt, int total)
{
    int idx = blockIdx.x * blockDim.x + threadIdx.x;
    if (idx >= total) return;
    int kk = idx & 3;
    int f  = (idx >> 2) & 127;
    int k4 = (idx >> 9) % 5;
    int c  = (idx / (4 * 128 * 5)) % 3;
    int l  = idx / (4 * 128 * 5 * 3);
    int k  = k4 * 4 + kk;
    dWt[idx] = dW[((long)(l * 3 + c) * 128 + f) * NRBF + k];
}

// ---------------------------------------------------------------------------
// CSR build
// ---------------------------------------------------------------------------
__global__ __launch_bounds__(256) void hist_kernel(
    const int* __restrict__ nbr, int* __restrict__ deg, int Ed)
{
    int e = blockIdx.x * blockDim.x + threadIdx.x;
    if (e >= Ed) return;
    int E = Ed >> 1;
    int i = (e < E) ? nbr[2 * e] : nbr[2 * (e - E) + 1];
    atomicAdd(&deg[i], 1);
}

__device__ inline int wave_incl_scan(int x, int lane)
{
    #pragma unroll
    for (int s = 1; s < 64; s <<= 1) {
        int y = __shfl_up(x, s, 64);
        if (lane >= s) x += y;
    }
    return x;
}

__global__ __launch_bounds__(1024) void scan_kernel(
    const int* __restrict__ deg, int* __restrict__ off,
    int* __restrict__ cursor, int N)
{
    __shared__ int wsum[16];
    __shared__ int carry_s;
    const int t = threadIdx.x;
    const int lane = t & 63;
    const int w = t >> 6;
    if (t == 0) { carry_s = 0; off[0] = 0; }
    __syncthreads();
    for (int base = 0; base < N; base += 1024) {
        int i = base + t;
        int x = (i < N) ? deg[i] : 0;
        int sc = wave_incl_scan(x, lane);
        if (lane == 63) wsum[w] = sc;
        __syncthreads();
        if (w == 0) {
            int v = (lane < 16) ? wsum[lane] : 0;
            int vs = wave_incl_scan(v, lane);
            if (lane < 16) wsum[lane] = vs;
        }
        __syncthreads();
        int waveoff = (w > 0) ? wsum[w - 1] : 0;
        int inc = sc + waveoff + carry_s;
        if (i < N) { off[i + 1] = inc; cursor[i] = inc - x; }
        __syncthreads();
        if (t == 1023) carry_s = inc;
        __syncthreads();
    }
}

__global__ __launch_bounds__(256) void scatter_geom_kernel(
    const int* __restrict__ nbr, const float* __restrict__ xyz,
    int* __restrict__ cursor, int* __restrict__ csr_j,
    float* __restrict__ csr_geo, float* __restrict__ csr_rbfe, int Ed)
{
    int e = blockIdx.x * blockDim.x + threadIdx.x;
    if (e >= Ed) return;
    int E = Ed >> 1;
    int i, j;
    if (e < E) { i = nbr[2 * e];         j = nbr[2 * e + 1]; }
    else       { int u = e - E; i = nbr[2 * u + 1]; j = nbr[2 * u]; }

    int p = atomicAdd(&cursor[i], 1);
    csr_j[p] = j;

    float rx = xyz[3 * j + 0] - xyz[3 * i + 0];
    float ry = xyz[3 * j + 1] - xyz[3 * i + 1];
    float rz = xyz[3 * j + 2] - xyz[3 * i + 2];
    float d   = sqrtf(rx * rx + ry * ry + rz * rz);
    float inv = 1.f / d;
    float ev = (d < 20.f) ? 0.5f * (__cosf(PI_F * d / 20.f) + 1.f) : 0.f;
    ((float4*)csr_geo)[p] = make_float4(rx * inv, ry * inv, rz * inv, ev);
    float base = PI_F * d / 20.f;
    #pragma unroll
    for (int k = 0; k < NRBF; ++k)
        csr_rbfe[(long)p * NRBF + k] = ev * __sinf((float)(k + 1) * base) * inv;
}

// ---------------------------------------------------------------------------
// Edge aggregation v4 — 16B/lane gathers, near-fp32 v precision:
//  - cgA ushort4 {ph0,ph1,ph2,vh0} (8B) + cgB uint2 {vh1|vh2<<16,
//    vl8_0|vl8_1<<8|vl8_2<<16} (8B): v = top-24-bits of fp32, decoded by
//    (vh<<16)|(vl8<<8) -> rel err <= 2^-15 (v3's bf16-hi 2^-8 failed absmax)
//  - dist coefficients: 60 fp32 in VGPRs, preloaded once per block
//  - rbf/geo loads wave-uniform (scalarized); 2-deep gather prefetch
// ---------------------------------------------------------------------------
__global__ __launch_bounds__(128, 4) void edge_aggr_kernel(
    const int* __restrict__ off, const int* __restrict__ csr_j,
    const float* __restrict__ csr_geo, const float* __restrict__ csr_rbfe,
    const float* __restrict__ dWt, const float* __restrict__ distb,
    const ushort4* __restrict__ cgA, const uint2* __restrict__ cgB,
    const float* __restrict__ vold,
    float* __restrict__ s, float* __restrict__ vnew,
    ushort_t* __restrict__ vnh, ushort_t* __restrict__ vnl, int N, int SP)
{
    const int f = threadIdx.x & 127;

    // 60 dist coefficients for this lane's f, in registers (static indexing)
    float4 cw[3][5];
    #pragma unroll
    for (int c = 0; c < 3; ++c)
        #pragma unroll
        for (int k4 = 0; k4 < 5; ++k4)
            cw[c][k4] = *(const float4*)(dWt + (long)((c * 5 + k4) * 512 + f * 4));
    float bb[3];
    bb[0] = distb[f]; bb[1] = distb[128 + f]; bb[2] = distb[256 + f];

    const float4* __restrict__ geo4 = (const float4*)csr_geo;
    const float4* __restrict__ v4   = (const float4*)vold;

    for (int node = blockIdx.x; node < N; node += gridDim.x) {
        const int p0 = off[node], p1 = off[node + 1];
        float ssum = 0.f, v0 = 0.f, v1 = 0.f, v2 = 0.f;

        // 2-deep gather prefetch pipeline
        ushort4 gA0 = make_ushort4(0, 0, 0, 0), gA1 = gA0;
        uint2 gB0 = make_uint2(0u, 0u), gB1 = gB0;
        if (p0 < p1) {
            long q = (long)csr_j[p0] * 128 + f;
            gA0 = cgA[q]; gB0 = cgB[q];
        }
        if (p0 + 1 < p1) {
            long q = (long)csr_j[p0 + 1] * 128 + f;
            gA1 = cgA[q]; gB1 = cgB[q];
        }
        for (int p = p0; p < p1; ++p) {
            ushort4 ga = gA0; uint2 gb = gB0;
            gA0 = gA1; gB0 = gB1;
            if (p + 2 < p1) {
                long q = (long)csr_j[p + 2] * 128 + f;
                gA1 = cgA[q]; gB1 = cgB[q];
            }
            float4 ge = geo4[p];                    // {ux,uy,uz,env}, uniform
            const float4* rb4 = (const float4*)(csr_rbfe + (long)p * NRBF);
            float4 rv[5];
            #pragma unroll
            for (int k4 = 0; k4 < 5; ++k4) rv[k4] = rb4[k4];   // uniform
            float w[3];
            #pragma unroll
            for (int c = 0; c < 3; ++c) {
                float acc = ge.w * bb[c];
                #pragma unroll
                for (int k4 = 0; k4 < 5; ++k4) {
                    float4 r = rv[k4], cv = cw[c][k4];
                    acc += r.x * cv.x + r.y * cv.y + r.z * cv.z + r.w * cv.w;
                }
                w[c] = acc;
            }
            float i0 = b2f(ga.x) * w[0];
            float i1 = b2f(ga.y) * w[1];
            float i2 = b2f(ga.z) * w[2];
            // v[j]: top-24-bit fp32 reconstruction
            float vx = u2f(((unsigned int)ga.w << 16) | ((gb.y & 0xffu) << 8));
            float vy = u2f(((gb.x & 0xffffu) << 16) | (((gb.y >> 8) & 0xffu) << 8));
            float vz = u2f((gb.x & 0xffff0000u) | (((gb.y >> 16) & 0xffu) << 8));
            ssum += i1;
            v0 += i2 * ge.x + i0 * vx;
            v1 += i2 * ge.y + i0 * vy;
            v2 += i2 * ge.z + i0 * vz;
        }
        long iv = (long)node * FEAT + f;
        s[iv] += ssum;
        float4 vc = v4[iv];                         // own node: fp32
        float n0 = vc.x + v0;
        float n1 = vc.y + v1;
        float n2 = vc.z + v2;
        ((float4*)vnew)[iv] = make_float4(n0, n1, n2, 0.f);
        unsigned short h0 = f2b(n0), h1 = f2b(n1), h2 = f2b(n2);
        vnh[iv]          = h0;  vnl[iv]          = f2b(n0 - b2f(h0));
        vnh[SP + iv]     = h1;  vnl[SP + iv]     = f2b(n1 - b2f(h1));
        vnh[2 * SP + iv] = h2;  vnl[2 * SP + iv] = f2b(n2 - b2f(h2));
    }
}

// ---------------------------------------------------------------------------
// Elementwise kernels
// ---------------------------------------------------------------------------
__global__ __launch_bounds__(256) void init_s_kernel(
    const float* __restrict__ cg_s, float* __restrict__ s,
    float* __restrict__ vA, unsigned int* __restrict__ cgA2,
    uint2* __restrict__ cgB, int nS, int nV)
{
    int idx = blockIdx.x * blockDim.x + threadIdx.x;
    if (idx < nS) {
        s[idx] = cg_s[idx];
        ((uint2*)cgA2)[idx] = make_uint2(0u, 0u);   // zero cgA (incl. vh0)
        cgB[idx] = make_uint2(0u, 0u);              // zero vh1|vh2, vl8s
    }
    if (idx < nV) vA[idx] = 0.f;
}

// final: if outv != null, v result goes interleaved to outv (and v not written)
// v / vnew are PACKED float4 [idx][4]; also emits 24-bit v into cgA.w / cgB
// for the next layer's edge gathers.
__global__ __launch_bounds__(256) void update_sv_kernel(
    float* __restrict__ s, float* __restrict__ v,
    const float* __restrict__ uv, const float* __restrict__ vv,
    const float* __restrict__ a, float* __restrict__ outv,
    ushort_t* __restrict__ cgA, uint2* __restrict__ cgB, int SP)
{
    int idx = blockIdx.x * blockDim.x + threadIdx.x;
    if (idx >= SP) return;
    int n = idx >> 7, g = idx & 127;
    float u0 = uv[idx], u1 = uv[SP + idx], u2 = uv[2 * SP + idx];
    float w0 = vv[idx], w1 = vv[SP + idx], w2 = vv[2 * SP + idx];
    long ab = (long)n * 384;
    float dot = u0 * w0 + u1 * w1 + u2 * w2;
    s[idx] += dot * a[ab + 128 + g] + a[ab + 256 + g];
    float g0 = a[ab + g];
    float4 xv = ((const float4*)v)[idx];
    float x0 = xv.x + u0 * g0;
    float x1 = xv.y + u1 * g0;
    float x2 = xv.z + u2 * g0;
    if (outv) {
        outv[(long)idx * 3 + 0] = x0;
        outv[(long)idx * 3 + 1] = x1;
        outv[(long)idx * 3 + 2] = x2;
    } else {
        ((float4*)v)[idx] = make_float4(x0, x1, x2, 0.f);
        unsigned int u0b = f2u(x0), u1b = f2u(x1), u2b = f2u(x2);
        cgA[(long)idx * 4 + 3] = (ushort_t)(u0b >> 16);
        unsigned int bx = (u1b >> 16) | (u2b & 0xffff0000u);
        unsigned int by = ((u0b >> 8) & 0xffu) |
                          (((u1b >> 8) & 0xffu) << 8) |
                          (((u2b >> 8) & 0xffu) << 16);
        cgB[idx] = make_uint2(bx, by);
    }
}

// ---------------------------------------------------------------------------
extern "C" void kernel_launch(void* const* d_in, const int* in_sizes, int n_in,
                              void* d_out, int out_size, void* d_ws, size_t ws_size,
                              hipStream_t stream)
{
    const float* xyz     = (const float*)d_in[0];
    const int*   nbr     = (const int*)  d_in[1];
    const float* cg_s    = (const float*)d_in[2];
    const float* msg_W1  = (const float*)d_in[3];
    const float* msg_b1  = (const float*)d_in[4];
    const float* msg_W2  = (const float*)d_in[5];
    const float* msg_b2  = (const float*)d_in[6];
    const float* dist_W  = (const float*)d_in[7];
    const float* dist_b  = (const float*)d_in[8];
    const float* upd_U   = (const float*)d_in[9];
    const float* upd_V   = (const float*)d_in[10];
    const float* upd_sW1 = (const float*)d_in[11];
    const float* upd_sb1 = (const float*)d_in[12];
    const float* upd_sW2 = (const float*)d_in[13];
    const float* upd_sb2 = (const float*)d_in[14];

    const int E  = in_sizes[1] / 2;
    const int Ed = 2 * E;
    const int N  = in_sizes[2] / FEAT;
    const int SP = N * FEAT;

    float* s    = (float*)d_out;
    float* outv = (float*)d_out + (long)SP;

    // workspace carve-up
    float* w = (float*)d_ws;
    size_t off_ = 0;
    auto alloc = [&](size_t nelem) {
        float* p = w + off_;
        off_ += (nelem + 255) & ~(size_t)255;
        return p;
    };
    auto allocb = [&](size_t nelem) {
        return (ushort_t*)alloc((nelem + 1) / 2);
    };
    int*   deg      = (int*)alloc((size_t)N);
    int*   off      = (int*)alloc((size_t)N + 1);
    int*   cursor   = (int*)alloc((size_t)N);
    int*   csr_j    = (int*)alloc((size_t)Ed);
    float* csr_geo  = alloc((size_t)Ed * 4);
    float* csr_rbfe = alloc((size_t)Ed * NRBF);
    float* a_buf    = alloc((size_t)N * 384);
    float* u_v      = alloc((size_t)3 * SP);
    float* v_v      = alloc((size_t)3 * SP);
    float* vA       = alloc((size_t)4 * SP);   // packed [idx][4] fp32
    float* vB       = alloc((size_t)4 * SP);   // packed [idx][4] fp32
    float* dWt      = alloc((size_t)NCONV * 3 * NRBF * FEAT);
    ushort_t* cgA   = allocb((size_t)N * 512); // [node][128] us4 {ph0,ph1,ph2,vh0}
    uint2* cgB      = (uint2*)alloc((size_t)2 * SP); // [node][128] {vh1|vh2, vl8x3}
    ushort_t* vnh   = allocb((size_t)3 * SP);
    ushort_t* vnl   = allocb((size_t)3 * SP);
    const int n1 = NCONV * FEAT * FEAT;
    const int n2 = NCONV * 3 * FEAT * FEAT;
    const int n3 = NCONV * FEAT * 2 * FEAT;
    ushort_t* w1h  = allocb((size_t)n1);
    ushort_t* w1l  = allocb((size_t)n1);
    ushort_t* w2h  = allocb((size_t)n2);
    ushort_t* w2l  = allocb((size_t)n2);
    ushort_t* uh   = allocb((size_t)n1);
    ushort_t* ul   = allocb((size_t)n1);
    ushort_t* vh   = allocb((size_t)n1);
    ushort_t* vl   = allocb((size_t)n1);
    ushort_t* sw1h = allocb((size_t)n3);
    ushort_t* sw1l = allocb((size_t)n3);
    ushort_t* sw2h = allocb((size_t)n2);
    ushort_t* sw2l = allocb((size_t)n2);
    (void)ws_size; (void)n_in; (void)out_size;

    // weight split (once per launch)
    split_kernel<<<(n1 + 255) / 256, 256, 0, stream>>>(msg_W1, w1h, w1l, n1);
    split_kernel<<<(n2 + 255) / 256, 256, 0, stream>>>(msg_W2, w2h, w2l, n2);
    split_kernel<<<(n1 + 255) / 256, 256, 0, stream>>>(upd_U, uh, ul, n1);
    split_kernel<<<(n1 + 255) / 256, 256, 0, stream>>>(upd_V, vh, vl, n1);
    split_kernel<<<(n3 + 255) / 256, 256, 0, stream>>>(upd_sW1, sw1h, sw1l, n3);
    split_kernel<<<(n2 + 255) / 256, 256, 0, stream>>>(upd_sW2, sw2h, sw2l, n2);

    // dist_W transpose (once per launch, all layers)
    {
        int total = NCONV * 3 * NRBF * FEAT;
        transpose_dw_kernel<<<(total + 255) / 256, 256, 0, stream>>>(
            dist_W, dWt, total);
    }

    // init s <- cg_s, vA <- 0, cgA/cgB v-slots <- 0
    {
        int n = 4 * SP;
        init_s_kernel<<<(n + 255) / 256, 256, 0, stream>>>(
            cg_s, s, vA, (unsigned int*)cgA, cgB, SP, n);
    }

    // CSR build (once per launch)
    hipMemsetAsync(deg, 0, (size_t)N * sizeof(int), stream);
    hist_kernel<<<(Ed + 255) / 256, 256, 0, stream>>>(nbr, deg, Ed);
    scan_kernel<<<1, 1024, 0, stream>>>(deg, off, cursor, N);
    scatter_geom_kernel<<<(Ed + 255) / 256, 256, 0, stream>>>(
        nbr, xyz, cursor, csr_j, csr_geo, csr_rbfe, Ed);

    float* vold = vA;
    float* vnew = vB;
    dim3 gM((N + 127) / 128, 1);
    dim3 gUV((3 * N + 127) / 128, 2);
    int edgeGrid = 4096;
    if (edgeGrid > N) edgeGrid = N;

    for (int l = 0; l < NCONV; ++l) {
        const float* b1  = msg_b1  + (long)l * FEAT;
        const float* b2  = msg_b2  + (long)l * 3 * FEAT;
        const float* db  = dist_b  + (long)l * 3 * FEAT;
        const float* sb1 = upd_sb1 + (long)l * FEAT;
        const float* sb2 = upd_sb2 + (long)l * 3 * FEAT;
        const long o1 = (long)l * FEAT * FEAT;
        const long o2 = (long)l * 3 * FEAT * FEAT;
        const long o3 = (long)l * FEAT * 2 * FEAT;

        // fused phi-MLP: s -> (h in LDS) -> cgA.xyz (packed bf16 hi)
        mlp_fused_kernel<<<gM, 256, 0, stream>>>(
            s, nullptr, w1h + o1, w1l + o1, b1, w2h + o2, w2l + o2, b2,
            cgA, nullptr, N, FEAT, SP);

        // atomic-free message aggregation (v4)
        edge_aggr_kernel<<<edgeGrid, 128, 0, stream>>>(
            off, csr_j, csr_geo, csr_rbfe, dWt + (long)l * 3 * NRBF * FEAT, db,
            (const ushort4*)cgA, cgB, vold, s, vnew, vnh, vnl, N, SP);

        // u_v / v_v in one dispatch (y=0 -> U, y=1 -> V)
        gemm_ps_kernel<<<gUV, 256, 0, stream>>>(
            vnh, vnl, uh + o1, ul + o1, vh + o1, vl + o1,
            u_v, v_v, 3 * N, FEAT);

        // fused gate-MLP: [s | norm(v_v)] -> (h in LDS) -> a_buf (fp32)
        mlp_fused_kernel<<<gM, 256, 0, stream>>>(
            s, v_v, sw1h + o3, sw1l + o3, sb1, sw2h + o2, sw2l + o2, sb2,
            nullptr, a_buf, N, 2 * FEAT, SP);

        // final update; last layer writes v interleaved straight to output
        float* ov = (l == NCONV - 1) ? outv : nullptr;
        update_sv_kernel<<<(SP + 255) / 256, 256, 0, stream>>>(
            s, vnew, u_v, v_v, a_buf, ov, cgA, cgB, SP);

        float* tmp = vold; vold = vnew; vnew = tmp;
    }
}